// Round 5
// baseline (287.408 us; speedup 1.0000x reference)
//
#include <hip/hip_runtime.h>
#include <hip/hip_bf16.h>

typedef __bf16 bf16x8 __attribute__((ext_vector_type(8)));
typedef float f32x4 __attribute__((ext_vector_type(4)));

#define MFMA16(a,b,c) __builtin_amdgcn_mfma_f32_16x16x32_bf16(a,b,c,0,0,0)
#define GLL16(src, dst) __builtin_amdgcn_global_load_lds( \
    (const __attribute__((address_space(1))) unsigned int*)(src), \
    (__attribute__((address_space(3))) unsigned int*)(dst), 16, 0, 0)
#define WAIT_VM(n)  asm volatile("s_waitcnt vmcnt(" #n ")")
#define BAR() __builtin_amdgcn_s_barrier()

__device__ inline unsigned int pack_bf16(float a, float b) {
    unsigned short ua = __builtin_bit_cast(unsigned short, (__bf16)a);
    unsigned short ub = __builtin_bit_cast(unsigned short, (__bf16)b);
    return ((unsigned int)ub << 16) | ua;
}
__device__ inline short bf_s(float v) {
    __bf16 b = (__bf16)v;
    return __builtin_bit_cast(short, b);
}

// ---------------------------------------------------------------------------
// Fused fp32->bf16: x -> xb, Wq/Wk/Wv -> Wb rows [0,2048)/[2048,2560)/[2560,3072)
// ---------------------------------------------------------------------------
__global__ void cvt_all(const float* __restrict__ x,  const float* __restrict__ wq,
                        const float* __restrict__ wk, const float* __restrict__ wv,
                        __bf16* __restrict__ xb, __bf16* __restrict__ wb) {
    long i = (long)(blockIdx.x * blockDim.x + threadIdx.x) * 8;
    const float* src; __bf16* dst;
    if (i < 8388608)       { src = x  + i;              dst = xb + i; }
    else if (i < 12582912) { src = wq + (i - 8388608);  dst = wb + (i - 8388608); }
    else if (i < 13631488) { src = wk + (i - 12582912); dst = wb + (i - 12582912 + 4194304); }
    else                   { src = wv + (i - 13631488); dst = wb + (i - 13631488 + 5242880); }
    float4 a = *(const float4*)src;
    float4 b = *(const float4*)(src + 4);
    bf16x8 r;
    r[0] = (__bf16)a.x; r[1] = (__bf16)a.y; r[2] = (__bf16)a.z; r[3] = (__bf16)a.w;
    r[4] = (__bf16)b.x; r[5] = (__bf16)b.y; r[6] = (__bf16)b.z; r[7] = (__bf16)b.w;
    *(bf16x8*)dst = r;
}

// ---------------------------------------------------------------------------
// Fused QKV GEMM v3: 256x256 tile, BK=32, TRIPLE-buffered frag-order LDS
// (96 KB), FREE-FLOW loop: one barrier per K-tile, no intra-tile barriers,
// no explicit lgkm drains. Rationale (round-4 counters): the phased schedule
// strictly alternated LDS drain (~2300 cyc/CU/tile) and MFMA (~2480) giving
// 7275 cyc/tile measured; free-flow lets the compiler's fine-grained lgkmcnt
// overlap them. Triple buffer => tile t+2 stages into buf (t-1)%3, never the
// buffer read this tile => no WAR barrier. Counted vmcnt(4): newest tile's
// 4 loads stay in flight across the barrier (never 0 in steady loop).
// Grid 16x12=192, 512 thr (8 waves, 2Mx4N), per-wave out 128x64.
// Per tile/wave: 12 ds_read_b128 (A8+B4), 32 MFMA, 4 GLL16.
// Epilogue routes by tn: tn<8 Q row-major (scaled); 8-9 K frag-order;
// 10-11 V frag-order (identical to verified round-0/3 formulas).
// ---------------------------------------------------------------------------
__global__ __launch_bounds__(512, 2) void gemm_qkv(const __bf16* __restrict__ A,
                                                   const __bf16* __restrict__ B,
                                                   __bf16* __restrict__ Qb,
                                                   __bf16* __restrict__ Kf,
                                                   __bf16* __restrict__ Vf,
                                                   float qscale) {
    const int K = 2048;
    const int NT = 64;                 // K-tiles of 32
    __shared__ __bf16 As[3 * 8192];    // 48 KB: [buf][mb 0..15][512 frag-order]
    __shared__ __bf16 Bs[3 * 8192];    // 48 KB: [buf][nb 0..15][512]

    int tid = threadIdx.x;
    int wave = tid >> 6, lane = tid & 63;
    int quad = lane >> 4, l16 = lane & 15;
    int wr = wave >> 2, wc = wave & 3;

    int tm = blockIdx.x & 15, tn = blockIdx.x >> 4;

    const __bf16* Ab = A + (size_t)tm * 256 * K + (size_t)l16 * K + quad * 8;
    const __bf16* Bb = B + (size_t)tn * 256 * K + (size_t)l16 * K + quad * 8;

    // stage one K-tile (A 16KB + B 16KB) into buffer buf: 4 GLL16/thread
    auto stage = [&](int kt, int buf) {
#pragma unroll
        for (int r = 0; r < 2; ++r) {
            int mb = r * 8 + wave;     // 0..15: one 16x32 subtile per (r,wave)
            GLL16(Ab + (size_t)mb * 16 * K + kt, As + buf * 8192 + mb * 512 + lane * 8);
            GLL16(Bb + (size_t)mb * 16 * K + kt, Bs + buf * 8192 + mb * 512 + lane * 8);
        }
    };

    f32x4 acc[8][4] = {};

    // prologue: tile0 -> buf0, tile1 -> buf1; tile0 landed, tile1 in flight
    stage(0, 0);
    stage(32, 1);
    WAIT_VM(4);
    BAR();

    int cur = 0, nxt = 2;
    for (int t = 0; t < NT; ++t) {
        // stage tile t+2 into buf (t+2)%3 == (t-1)%3: its readers (tile t-1)
        // completed all reads before the end-of-(t-1) barrier -> WAR-safe.
        if (t + 2 < NT) stage((t + 2) << 5, nxt);

        const __bf16* Ac = As + cur * 8192;
        const __bf16* Bc = Bs + cur * 8192;
        bf16x8 a[8], b[4];
#pragma unroll
        for (int m = 0; m < 8; ++m)
            a[m] = *(const bf16x8*)(Ac + (wr * 8 + m) * 512 + lane * 8);
#pragma unroll
        for (int n = 0; n < 4; ++n)
            b[n] = *(const bf16x8*)(Bc + (wc * 4 + n) * 512 + lane * 8);
        // 32 independent MFMAs; compiler interleaves with the ds_reads above
        // via fine-grained lgkmcnt — matrix pipe starts after first frags.
#pragma unroll
        for (int m = 0; m < 8; ++m)
#pragma unroll
            for (int n = 0; n < 4; ++n)
                acc[m][n] = MFMA16(a[m], b[n], acc[m][n]);

        // tile t+1's loads (staged during t-1, older than the 4 just issued)
        // must be landed; tile t+2's 4 stay in flight.
        if (t + 2 < NT)      WAIT_VM(4);
        else if (t + 1 < NT) WAIT_VM(0);
        BAR();
        cur = (cur == 2) ? 0 : cur + 1;
        nxt = (nxt == 2) ? 0 : nxt + 1;
    }

    // ---- epilogue: route by tn (block-uniform) ----
#pragma unroll
    for (int m = 0; m < 8; ++m) {
        int row0 = tm * 256 + wr * 128 + m * 16 + quad * 4;
        int bb = row0 >> 11, tok0 = row0 & 2047;
#pragma unroll
        for (int n = 0; n < 4; ++n) {
            int col = tn * 256 + wc * 64 + n * 16 + l16;
            if (tn < 8) {                        // ---- Q, row-major ----
#pragma unroll
                for (int r = 0; r < 4; ++r)
                    Qb[(size_t)(row0 + r) * 2048 + col] = (__bf16)(acc[m][n][r] * qscale);
            } else if (tn < 10) {                // ---- K frag-order ----
                int d_all = col - 2048;
                int g = d_all >> 7, dd = d_all & 127;
                int dt = dd >> 5, q4 = (dd >> 3) & 3, jj = dd & 7;
                int tb = tok0 >> 4, tl0 = tok0 & 15;
                __bf16* base = Kf + ((((size_t)(bb * 4 + g) * 128 + tb) * 4 + dt) * 512)
                               + (q4 * 16 + tl0) * 8 + jj;
#pragma unroll
                for (int r = 0; r < 4; ++r)
                    base[r * 8] = (__bf16)acc[m][n][r];
            } else {                             // ---- V frag-order ----
                int d_all = col - 2560;
                int g = d_all >> 7, dd = d_all & 127;
                int nto = dd >> 4, dl = dd & 15;
                int ch = tok0 >> 6, kk = (tok0 >> 5) & 1;
                int q4v = (tok0 >> 3) & 3, jv0 = tok0 & 7;
                size_t off = ((((size_t)(bb * 4 + g) * 32 + ch) * 16) + nto * 2 + kk) * 512
                             + (q4v * 16 + dl) * 8 + jv0;
                short4 pk;
                pk.x = bf_s(acc[m][n][0]); pk.y = bf_s(acc[m][n][1]);
                pk.z = bf_s(acc[m][n][2]); pk.w = bf_s(acc[m][n][3]);
                *(short4*)(Vf + off) = pk;
            }
        }
    }
}

// ---------------------------------------------------------------------------
// Flash attention — UNCHANGED from round 4 (clean attribution; if gemm drops
// below ~95 µs this kernel enters the rocprof top-5 and gets diagnosed next).
// ---------------------------------------------------------------------------
__global__ __launch_bounds__(256) void attn_mfma(const __bf16* __restrict__ Q,
                                                 const __bf16* __restrict__ Kf,
                                                 const __bf16* __restrict__ Vf,
                                                 float* __restrict__ O) {
    const int T = 2048, CM = 2048, HD = 128;
    __shared__ __bf16 Ks[2 * 8192];   // 32 KB: buf | fb = t*4+dt
    __shared__ __bf16 Vs[2 * 8192];   // 32 KB: buf | fb = nto*2+kk
    __shared__ __bf16 Pl[8192];       // 4 KB/wave: fb = mt*2+kk

    int tid = threadIdx.x;
    int wave = tid >> 6, lane = tid & 63;
    int quad = lane >> 4, l16 = lane & 15;

    int bg = blockIdx.x & 7;
    int slot = blockIdx.x >> 3;
    int qb = (slot < 32) ? (63 - slot) : (slot - 32);
    int b = bg >> 2, g = bg & 3;
    int h = g * 4 + wave;
    int q0 = qb * 32;

    bf16x8 qf[2][4];
    const __bf16* qbase = Q + (size_t)b * T * CM + (size_t)h * HD;
#pragma unroll
    for (int nt = 0; nt < 2; ++nt)
#pragma unroll
        for (int dt = 0; dt < 4; ++dt)
            qf[nt][dt] = *(const bf16x8*)(qbase + (size_t)(q0 + nt * 16 + l16) * CM
                                          + dt * 32 + quad * 8);

    const __bf16* kcb = Kf + (size_t)(b * 4 + g) * 262144;
    const __bf16* vcb = Vf + (size_t)(b * 4 + g) * 262144;

    float m_r[2] = {-1e30f, -1e30f}, l_r[2] = {0.f, 0.f};
    f32x4 o_acc[2][8] = {};
    __bf16* Pw = Pl + wave * 2048;

    auto stage_kv = [&](int ch, int buf) {
        const __bf16* kg = kcb + ch * 8192 + wave * 2048 + lane * 8;
        const __bf16* vg = vcb + ch * 8192 + wave * 2048 + lane * 8;
        __bf16* kl = Ks + buf * 8192 + wave * 2048 + lane * 8;
        __bf16* vl = Vs + buf * 8192 + wave * 2048 + lane * 8;
#pragma unroll
        for (int i = 0; i < 4; ++i) GLL16(kg + i * 512, kl + i * 512);
#pragma unroll
        for (int i = 0; i < 4; ++i) GLL16(vg + i * 512, vl + i * 512);
    };

    int nch = (qb >> 1) + 1;
    stage_kv(0, 0);
    for (int ch = 0; ch < nch; ++ch) {
        // barrier #1: every wave finished reading buf (ch+1)&1 (= chunk ch-1)
        BAR();
        if (ch + 1 < nch) {
            stage_kv(ch + 1, (ch + 1) & 1);
            WAIT_VM(8);   // chunk ch's 8 loads older than the 8 just issued
        } else {
            WAIT_VM(0);
        }
        // barrier #2: rendezvous -> ALL waves' chunk-ch loads are in LDS
        BAR();

        const __bf16* Kb = Ks + (ch & 1) * 8192;
        const __bf16* Vb = Vs + (ch & 1) * 8192;

        // ---- S^T = K·Q^T ----
        f32x4 st[2][4] = {};
        __builtin_amdgcn_s_setprio(1);
#pragma unroll
        for (int t = 0; t < 4; ++t)
#pragma unroll
            for (int dt = 0; dt < 4; ++dt) {
                bf16x8 kfv = *(const bf16x8*)(Kb + (t * 4 + dt) * 512 + lane * 8);
                st[0][t] = MFMA16(kfv, qf[0][dt], st[0][t]);
                st[1][t] = MFMA16(kfv, qf[1][dt], st[1][t]);
            }
        __builtin_amdgcn_s_setprio(0);

        bool diag = (ch == nch - 1);
        float alpha[2];
#pragma unroll
        for (int nt = 0; nt < 2; ++nt) {
            if (diag) {
                int qg = q0 + nt * 16 + l16;
#pragma unroll
                for (int t = 0; t < 4; ++t)
#pragma unroll
                    for (int r = 0; r < 4; ++r)
                        if (ch * 64 + t * 16 + quad * 4 + r > qg) st[nt][t][r] = -1e30f;
            }
            float cmax = -1e30f;
#pragma unroll
            for (int t = 0; t < 4; ++t)
                cmax = fmaxf(cmax, fmaxf(fmaxf(st[nt][t][0], st[nt][t][1]),
                                         fmaxf(st[nt][t][2], st[nt][t][3])));
            cmax = fmaxf(cmax, __shfl_xor(cmax, 16));
            cmax = fmaxf(cmax, __shfl_xor(cmax, 32));
            float mnew = fmaxf(m_r[nt], cmax);
            alpha[nt] = __expf(m_r[nt] - mnew);
            m_r[nt] = mnew;
            float ps = 0.f;
#pragma unroll
            for (int t = 0; t < 4; ++t) {
                float p0 = __expf(st[nt][t][0] - mnew);
                float p1 = __expf(st[nt][t][1] - mnew);
                float p2 = __expf(st[nt][t][2] - mnew);
                float p3 = __expf(st[nt][t][3] - mnew);
                ps += (p0 + p1) + (p2 + p3);
                int off = (nt * 2 + (t >> 1)) * 512 + ((t & 1) * 2 + (quad >> 1)) * 128
                          + l16 * 8 + (quad & 1) * 4;
                unsigned long long pk =
                    (unsigned long long)pack_bf16(p0, p1) |
                    ((unsigned long long)pack_bf16(p2, p3) << 32);
                *(unsigned long long*)(Pw + off) = pk;
            }
            ps += __shfl_xor(ps, 16);
            ps += __shfl_xor(ps, 32);
            l_r[nt] = l_r[nt] * alpha[nt] + ps;
        }

        // ---- rescale O ----
#pragma unroll
        for (int mt = 0; mt < 2; ++mt)
#pragma unroll
            for (int r = 0; r < 4; ++r) {
                float alr = __shfl(alpha[mt], quad * 4 + r);
#pragma unroll
                for (int nto = 0; nto < 8; ++nto)
                    o_acc[mt][nto][r] *= alr;
            }

        // ---- O += P·V (P wave-private: no barrier; lgkmcnt orders WAR/RAW) ----
        __builtin_amdgcn_s_setprio(1);
#pragma unroll
        for (int mt = 0; mt < 2; ++mt)
#pragma unroll
            for (int kk = 0; kk < 2; ++kk) {
                bf16x8 pf = *(const bf16x8*)(Pw + (mt * 2 + kk) * 512 + lane * 8);
#pragma unroll
                for (int nto = 0; nto < 8; ++nto) {
                    bf16x8 vf = *(const bf16x8*)(Vb + (nto * 2 + kk) * 512 + lane * 8);
                    o_acc[mt][nto] = MFMA16(pf, vf, o_acc[mt][nto]);
                }
            }
        __builtin_amdgcn_s_setprio(0);
    }

    float* obase = O + (size_t)b * T * CM + (size_t)h * HD;
#pragma unroll
    for (int mt = 0; mt < 2; ++mt) {
        float invl = 1.f / l_r[mt];
#pragma unroll
        for (int r = 0; r < 4; ++r) {
            float ir = __shfl(invl, quad * 4 + r);
            float* orow = obase + (size_t)(q0 + 16 * mt + quad * 4 + r) * CM;
#pragma unroll
            for (int nto = 0; nto < 8; ++nto)
                orow[nto * 16 + l16] = o_acc[mt][nto][r] * ir;
        }
    }
}

extern "C" void kernel_launch(void* const* d_in, const int* in_sizes, int n_in,
                              void* d_out, int out_size, void* d_ws, size_t ws_size,
                              hipStream_t stream) {
    const float* x  = (const float*)d_in[0];
    const float* Wq = (const float*)d_in[1];
    const float* Wk = (const float*)d_in[2];
    const float* Wv = (const float*)d_in[3];
    float* out = (float*)d_out;

    const float qscale = 0.08838834764831845f;  // 128^-0.5

    __bf16* xb = (__bf16*)d_ws;              // 8M elems
    __bf16* Wb = xb + 8388608;               // 6M  [3072][2048] = Wq|Wk|Wv
    __bf16* Qb = Wb + 6291456;               // 8M  [4096][2048]
    __bf16* Kfr = Qb + 8388608;              // 2M  frag-order K
    __bf16* Vfr = Kfr + 2097152;             // 2M  frag-order V

    cvt_all<<<7168, 256, 0, stream>>>(x, Wq, Wk, Wv, xb, Wb);
    gemm_qkv<<<192, 512, 0, stream>>>(xb, Wb, Qb, Kfr, Vfr, qscale);
    attn_mfma<<<512, 256, 0, stream>>>(Qb, Kfr, Vfr, out);
}

// Round 7
// 273.071 us; speedup vs baseline: 1.0525x; 1.0525x over previous
//
#include <hip/hip_runtime.h>
#include <hip/hip_bf16.h>

typedef __bf16 bf16x8 __attribute__((ext_vector_type(8)));
typedef float f32x4 __attribute__((ext_vector_type(4)));

#define MFMA16(a,b,c) __builtin_amdgcn_mfma_f32_16x16x32_bf16(a,b,c,0,0,0)
#define GLL16(src, dst) __builtin_amdgcn_global_load_lds( \
    (const __attribute__((address_space(1))) unsigned int*)(src), \
    (__attribute__((address_space(3))) unsigned int*)(dst), 16, 0, 0)
#define WAIT_VM(n)  asm volatile("s_waitcnt vmcnt(" #n ")")
#define BAR() __builtin_amdgcn_s_barrier()

__device__ inline unsigned int pack_bf16(float a, float b) {
    unsigned short ua = __builtin_bit_cast(unsigned short, (__bf16)a);
    unsigned short ub = __builtin_bit_cast(unsigned short, (__bf16)b);
    return ((unsigned int)ub << 16) | ua;
}
__device__ inline short bf_s(float v) {
    __bf16 b = (__bf16)v;
    return __builtin_bit_cast(short, b);
}

// ---------------------------------------------------------------------------
// Fused fp32->bf16: x -> xb, Wq/Wk/Wv -> Wb rows [0,2048)/[2048,2560)/[2560,3072)
// ---------------------------------------------------------------------------
__global__ void cvt_all(const float* __restrict__ x,  const float* __restrict__ wq,
                        const float* __restrict__ wk, const float* __restrict__ wv,
                        __bf16* __restrict__ xb, __bf16* __restrict__ wb) {
    long i = (long)(blockIdx.x * blockDim.x + threadIdx.x) * 8;
    const float* src; __bf16* dst;
    if (i < 8388608)       { src = x  + i;              dst = xb + i; }
    else if (i < 12582912) { src = wq + (i - 8388608);  dst = wb + (i - 8388608); }
    else if (i < 13631488) { src = wk + (i - 12582912); dst = wb + (i - 12582912 + 4194304); }
    else                   { src = wv + (i - 13631488); dst = wb + (i - 13631488 + 5242880); }
    float4 a = *(const float4*)src;
    float4 b = *(const float4*)(src + 4);
    bf16x8 r;
    r[0] = (__bf16)a.x; r[1] = (__bf16)a.y; r[2] = (__bf16)a.z; r[3] = (__bf16)a.w;
    r[4] = (__bf16)b.x; r[5] = (__bf16)b.y; r[6] = (__bf16)b.z; r[7] = (__bf16)b.w;
    *(bf16x8*)dst = r;
}

// ---------------------------------------------------------------------------
// Fused QKV GEMM v4 (kept from round 6 — bisect lane A): round-0-verified
// 128x128/BK=32 one-syncthreads double-buffer loop, re-waved for occupancy.
// 512 thr = 8 waves (4Mx2N), per-wave out 32x64 = acc[2][4]; grid 768 =
// 3 blocks/CU = 6 waves/SIMD (round-5 lesson: per-CU FLOP/cyc tracks
// waves/SIMD — 1/3/4 -> 521/785/1423; co-resident blocks hide the drain).
// Per thread/iter: 1 GLL16 pair, 6 ds_read_b128, 8 MFMA. acc in AGPRs.
// Epilogue routes by tn (verbatim round-0 formulas): tn<16 Q row-major
// (scaled); 16-19 K frag-order; 20-23 V frag-order.
// ---------------------------------------------------------------------------
__global__ __launch_bounds__(512, 6) void gemm_qkv(const __bf16* __restrict__ A,
                                                   const __bf16* __restrict__ B,
                                                   __bf16* __restrict__ Qb,
                                                   __bf16* __restrict__ Kf,
                                                   __bf16* __restrict__ Vf,
                                                   float qscale) {
    const int K = 2048;
    __shared__ __bf16 As[2 * 4096];   // 16 KB: [buf][fb 0..7][512 frag-order]
    __shared__ __bf16 Bs[2 * 4096];   // 16 KB

    int tid = threadIdx.x;
    int wave = tid >> 6, lane = tid & 63;
    int quad = lane >> 4, l16 = lane & 15;
    int wr = wave >> 1, wc = wave & 1;   // 4x2 wave grid

    int tm = blockIdx.x & 31, tn = blockIdx.x >> 5;   // 32 x 24

    const __bf16* Abase = A + (size_t)tm * 128 * K + (size_t)l16 * K + quad * 8;
    const __bf16* Bbase = B + (size_t)tn * 128 * K + (size_t)l16 * K + quad * 8;

    f32x4 acc[2][4] = {};

    // each wave stages one 16x32 subtile of A and one of B (8 waves = 128 rows)
    auto stage = [&](int kt, int buf) {
        GLL16(Abase + (size_t)wave * 16 * K + kt, As + buf * 4096 + wave * 512 + lane * 8);
        GLL16(Bbase + (size_t)wave * 16 * K + kt, Bs + buf * 4096 + wave * 512 + lane * 8);
    };

    const int nk = K >> 5;   // 64
    stage(0, 0);
    for (int it = 0; it < nk; ++it) {
        __syncthreads();     // drains vmcnt -> buf it&1 fully staged; WAR-safe
        if (it + 1 < nk) stage((it + 1) << 5, (it + 1) & 1);
        const __bf16* Ab = As + (it & 1) * 4096;
        const __bf16* Bb = Bs + (it & 1) * 4096;
        bf16x8 af[2], bfr[4];
#pragma unroll
        for (int m = 0; m < 2; ++m)
            af[m] = *(const bf16x8*)(Ab + (wr * 2 + m) * 512 + lane * 8);
#pragma unroll
        for (int n = 0; n < 4; ++n)
            bfr[n] = *(const bf16x8*)(Bb + (wc * 4 + n) * 512 + lane * 8);
#pragma unroll
        for (int m = 0; m < 2; ++m)
#pragma unroll
            for (int n = 0; n < 4; ++n)
                acc[m][n] = MFMA16(af[m], bfr[n], acc[m][n]);
    }

    // ---- epilogue: route by tn (verbatim round-0 formulas) ----
#pragma unroll
    for (int m = 0; m < 2; ++m) {
        int row0 = tm * 128 + wr * 32 + m * 16 + quad * 4;
        int bb = row0 >> 11, tok0 = row0 & 2047;
#pragma unroll
        for (int n = 0; n < 4; ++n) {
            int col = tn * 128 + wc * 64 + n * 16 + l16;
            if (tn < 16) {                       // ---- Q, row-major ----
#pragma unroll
                for (int r = 0; r < 4; ++r)
                    Qb[(size_t)(row0 + r) * 2048 + col] = (__bf16)(acc[m][n][r] * qscale);
            } else if (tn < 20) {                // ---- K frag-order ----
                int d_all = col - 2048;
                int g = d_all >> 7, dd = d_all & 127;
                int dt = dd >> 5, q4 = (dd >> 3) & 3, jj = dd & 7;
                int tb = tok0 >> 4, tl0 = tok0 & 15;
                __bf16* base = Kf + ((((size_t)(bb * 4 + g) * 128 + tb) * 4 + dt) * 512)
                               + (q4 * 16 + tl0) * 8 + jj;
#pragma unroll
                for (int r = 0; r < 4; ++r)
                    base[r * 8] = (__bf16)acc[m][n][r];
            } else {                             // ---- V frag-order ----
                int d_all = col - 2560;
                int g = d_all >> 7, dd = d_all & 127;
                int nto = dd >> 4, dl = dd & 15;
                int ch = tok0 >> 6, kk = (tok0 >> 5) & 1;
                int q4v = (tok0 >> 3) & 3, jv0 = tok0 & 7;
                size_t off = ((((size_t)(bb * 4 + g) * 32 + ch) * 16) + nto * 2 + kk) * 512
                             + (q4v * 16 + dl) * 8 + jv0;
                short4 pk;
                pk.x = bf_s(acc[m][n][0]); pk.y = bf_s(acc[m][n][1]);
                pk.z = bf_s(acc[m][n][2]); pk.w = bf_s(acc[m][n][3]);
                *(short4*)(Vf + off) = pk;
            }
        }
    }
}

// ---------------------------------------------------------------------------
// Flash attention — REVERTED verbatim to the round-4/5 kernel (passed twice).
// Bisect lane B: round-6's 8-wave restructure raced under graph replay; this
// 4-wave version is the proven-correct baseline. If round 7 passes, the race
// is isolated to the 8-wave attn restructure.
// ---------------------------------------------------------------------------
__global__ __launch_bounds__(256) void attn_mfma(const __bf16* __restrict__ Q,
                                                 const __bf16* __restrict__ Kf,
                                                 const __bf16* __restrict__ Vf,
                                                 float* __restrict__ O) {
    const int T = 2048, CM = 2048, HD = 128;
    __shared__ __bf16 Ks[2 * 8192];   // 32 KB: buf | fb = t*4+dt
    __shared__ __bf16 Vs[2 * 8192];   // 32 KB: buf | fb = nto*2+kk
    __shared__ __bf16 Pl[8192];       // 4 KB/wave: fb = mt*2+kk

    int tid = threadIdx.x;
    int wave = tid >> 6, lane = tid & 63;
    int quad = lane >> 4, l16 = lane & 15;

    int bg = blockIdx.x & 7;
    int slot = blockIdx.x >> 3;
    int qb = (slot < 32) ? (63 - slot) : (slot - 32);
    int b = bg >> 2, g = bg & 3;
    int h = g * 4 + wave;
    int q0 = qb * 32;

    bf16x8 qf[2][4];
    const __bf16* qbase = Q + (size_t)b * T * CM + (size_t)h * HD;
#pragma unroll
    for (int nt = 0; nt < 2; ++nt)
#pragma unroll
        for (int dt = 0; dt < 4; ++dt)
            qf[nt][dt] = *(const bf16x8*)(qbase + (size_t)(q0 + nt * 16 + l16) * CM
                                          + dt * 32 + quad * 8);

    const __bf16* kcb = Kf + (size_t)(b * 4 + g) * 262144;
    const __bf16* vcb = Vf + (size_t)(b * 4 + g) * 262144;

    float m_r[2] = {-1e30f, -1e30f}, l_r[2] = {0.f, 0.f};
    f32x4 o_acc[2][8] = {};
    __bf16* Pw = Pl + wave * 2048;

    auto stage_kv = [&](int ch, int buf) {
        const __bf16* kg = kcb + ch * 8192 + wave * 2048 + lane * 8;
        const __bf16* vg = vcb + ch * 8192 + wave * 2048 + lane * 8;
        __bf16* kl = Ks + buf * 8192 + wave * 2048 + lane * 8;
        __bf16* vl = Vs + buf * 8192 + wave * 2048 + lane * 8;
#pragma unroll
        for (int i = 0; i < 4; ++i) GLL16(kg + i * 512, kl + i * 512);
#pragma unroll
        for (int i = 0; i < 4; ++i) GLL16(vg + i * 512, vl + i * 512);
    };

    int nch = (qb >> 1) + 1;
    stage_kv(0, 0);
    for (int ch = 0; ch < nch; ++ch) {
        // barrier #1: every wave finished reading buf (ch+1)&1 (= chunk ch-1)
        BAR();
        if (ch + 1 < nch) {
            stage_kv(ch + 1, (ch + 1) & 1);
            WAIT_VM(8);   // chunk ch's 8 loads older than the 8 just issued
        } else {
            WAIT_VM(0);
        }
        // barrier #2: rendezvous -> ALL waves' chunk-ch loads are in LDS
        BAR();

        const __bf16* Kb = Ks + (ch & 1) * 8192;
        const __bf16* Vb = Vs + (ch & 1) * 8192;

        // ---- S^T = K·Q^T ----
        f32x4 st[2][4] = {};
        __builtin_amdgcn_s_setprio(1);
#pragma unroll
        for (int t = 0; t < 4; ++t)
#pragma unroll
            for (int dt = 0; dt < 4; ++dt) {
                bf16x8 kfv = *(const bf16x8*)(Kb + (t * 4 + dt) * 512 + lane * 8);
                st[0][t] = MFMA16(kfv, qf[0][dt], st[0][t]);
                st[1][t] = MFMA16(kfv, qf[1][dt], st[1][t]);
            }
        __builtin_amdgcn_s_setprio(0);

        bool diag = (ch == nch - 1);
        float alpha[2];
#pragma unroll
        for (int nt = 0; nt < 2; ++nt) {
            if (diag) {
                int qg = q0 + nt * 16 + l16;
#pragma unroll
                for (int t = 0; t < 4; ++t)
#pragma unroll
                    for (int r = 0; r < 4; ++r)
                        if (ch * 64 + t * 16 + quad * 4 + r > qg) st[nt][t][r] = -1e30f;
            }
            float cmax = -1e30f;
#pragma unroll
            for (int t = 0; t < 4; ++t)
                cmax = fmaxf(cmax, fmaxf(fmaxf(st[nt][t][0], st[nt][t][1]),
                                         fmaxf(st[nt][t][2], st[nt][t][3])));
            cmax = fmaxf(cmax, __shfl_xor(cmax, 16));
            cmax = fmaxf(cmax, __shfl_xor(cmax, 32));
            float mnew = fmaxf(m_r[nt], cmax);
            alpha[nt] = __expf(m_r[nt] - mnew);
            m_r[nt] = mnew;
            float ps = 0.f;
#pragma unroll
            for (int t = 0; t < 4; ++t) {
                float p0 = __expf(st[nt][t][0] - mnew);
                float p1 = __expf(st[nt][t][1] - mnew);
                float p2 = __expf(st[nt][t][2] - mnew);
                float p3 = __expf(st[nt][t][3] - mnew);
                ps += (p0 + p1) + (p2 + p3);
                int off = (nt * 2 + (t >> 1)) * 512 + ((t & 1) * 2 + (quad >> 1)) * 128
                          + l16 * 8 + (quad & 1) * 4;
                unsigned long long pk =
                    (unsigned long long)pack_bf16(p0, p1) |
                    ((unsigned long long)pack_bf16(p2, p3) << 32);
                *(unsigned long long*)(Pw + off) = pk;
            }
            ps += __shfl_xor(ps, 16);
            ps += __shfl_xor(ps, 32);
            l_r[nt] = l_r[nt] * alpha[nt] + ps;
        }

        // ---- rescale O ----
#pragma unroll
        for (int mt = 0; mt < 2; ++mt)
#pragma unroll
            for (int r = 0; r < 4; ++r) {
                float alr = __shfl(alpha[mt], quad * 4 + r);
#pragma unroll
                for (int nto = 0; nto < 8; ++nto)
                    o_acc[mt][nto][r] *= alr;
            }

        // ---- O += P·V (P wave-private: no barrier; lgkmcnt orders WAR/RAW) ----
        __builtin_amdgcn_s_setprio(1);
#pragma unroll
        for (int mt = 0; mt < 2; ++mt)
#pragma unroll
            for (int kk = 0; kk < 2; ++kk) {
                bf16x8 pf = *(const bf16x8*)(Pw + (mt * 2 + kk) * 512 + lane * 8);
#pragma unroll
                for (int nto = 0; nto < 8; ++nto) {
                    bf16x8 vf = *(const bf16x8*)(Vb + (nto * 2 + kk) * 512 + lane * 8);
                    o_acc[mt][nto] = MFMA16(pf, vf, o_acc[mt][nto]);
                }
            }
        __builtin_amdgcn_s_setprio(0);
    }

    float* obase = O + (size_t)b * T * CM + (size_t)h * HD;
#pragma unroll
    for (int mt = 0; mt < 2; ++mt) {
        float invl = 1.f / l_r[mt];
#pragma unroll
        for (int r = 0; r < 4; ++r) {
            float ir = __shfl(invl, quad * 4 + r);
            float* orow = obase + (size_t)(q0 + 16 * mt + quad * 4 + r) * CM;
#pragma unroll
            for (int nto = 0; nto < 8; ++nto)
                orow[nto * 16 + l16] = o_acc[mt][nto][r] * ir;
        }
    }
}

extern "C" void kernel_launch(void* const* d_in, const int* in_sizes, int n_in,
                              void* d_out, int out_size, void* d_ws, size_t ws_size,
                              hipStream_t stream) {
    const float* x  = (const float*)d_in[0];
    const float* Wq = (const float*)d_in[1];
    const float* Wk = (const float*)d_in[2];
    const float* Wv = (const float*)d_in[3];
    float* out = (float*)d_out;

    const float qscale = 0.08838834764831845f;  // 128^-0.5

    __bf16* xb = (__bf16*)d_ws;              // 8M elems
    __bf16* Wb = xb + 8388608;               // 6M  [3072][2048] = Wq|Wk|Wv
    __bf16* Qb = Wb + 6291456;               // 8M  [4096][2048]
    __bf16* Kfr = Qb + 8388608;              // 2M  frag-order K
    __bf16* Vfr = Kfr + 2097152;             // 2M  frag-order V

    cvt_all<<<7168, 256, 0, stream>>>(x, Wq, Wk, Wv, xb, Wb);
    gemm_qkv<<<768, 512, 0, stream>>>(xb, Wb, Qb, Kfr, Vfr, qscale);
    attn_mfma<<<512, 256, 0, stream>>>(Qb, Kfr, Vfr, out);
}

// Round 8
// 231.180 us; speedup vs baseline: 1.2432x; 1.1812x over previous
//
#include <hip/hip_runtime.h>
#include <hip/hip_bf16.h>

typedef __bf16 bf16x8 __attribute__((ext_vector_type(8)));
typedef float f32x4 __attribute__((ext_vector_type(4)));

#define MFMA16(a,b,c) __builtin_amdgcn_mfma_f32_16x16x32_bf16(a,b,c,0,0,0)
#define GLL16(src, dst) __builtin_amdgcn_global_load_lds( \
    (const __attribute__((address_space(1))) unsigned int*)(src), \
    (__attribute__((address_space(3))) unsigned int*)(dst), 16, 0, 0)
#define WAIT_VM(n)  asm volatile("s_waitcnt vmcnt(" #n ")")
#define BAR() __builtin_amdgcn_s_barrier()

__device__ inline unsigned int pack_bf16(float a, float b) {
    unsigned short ua = __builtin_bit_cast(unsigned short, (__bf16)a);
    unsigned short ub = __builtin_bit_cast(unsigned short, (__bf16)b);
    return ((unsigned int)ub << 16) | ua;
}
__device__ inline short bf_s(float v) {
    __bf16 b = (__bf16)v;
    return __builtin_bit_cast(short, b);
}

// ---------------------------------------------------------------------------
// cvt v2: fp32 -> bf16 AND re-tile into frag-tile order.
// Layout: row-block rb (16 rows) x k-block kb (32 k) tiles of 512 elems at
// base (rb*64+kb)*512; within-tile off = ((k>>3)&3)*128 + (row&15)*8 + (k&7)
// == the exact LDS frag order gemm stages, so gemm's GLL16 sources become
// CONTIGUOUS 1KB blocks (round-7 theory: 16-line/4KB-stride staging pattern
// is gemm's invariant 20%-MfmaUtil bottleneck).
// Block (rb 0..447, ks 0..15): 16 rows x 128 k. Thread t: row=t&15,
// k8=ks*16+(t>>4). Reads: wave covers 16 full lines; writes: threads 0-15
// contiguous 256B -> wave writes contiguous 1KB.
// rb<256: x -> xb ; rb>=256: Wq|Wk|Wv rows -> wb (boundaries 2048/2560 are
// multiples of 16 -> each row-block within one source).
// ---------------------------------------------------------------------------
__global__ __launch_bounds__(256) void cvt_all(const float* __restrict__ x,
                                               const float* __restrict__ wq,
                                               const float* __restrict__ wk,
                                               const float* __restrict__ wv,
                                               __bf16* __restrict__ xb,
                                               __bf16* __restrict__ wb) {
    int bid = blockIdx.x;
    int rb = bid >> 4, ks = bid & 15;
    int t = threadIdx.x;
    int row = t & 15;                 // row within 16-row block
    int k8 = ks * 16 + (t >> 4);      // 8-elem k-group, 0..255
    int k = k8 * 8;

    const float* src;
    __bf16* dptr;
    size_t tin = (size_t)(k8 >> 2) * 512 + (size_t)(k8 & 3) * 128 + row * 8;
    if (rb < 256) {                   // ---- x -> xb ----
        src  = x + (size_t)(rb * 16 + row) * 2048 + k;
        dptr = xb + (size_t)rb * 32768 + tin;
    } else {                          // ---- W -> wb ----
        int wr = (rb - 256) * 16 + row;
        if (wr < 2048)      src = wq + (size_t)wr * 2048 + k;
        else if (wr < 2560) src = wk + (size_t)(wr - 2048) * 2048 + k;
        else                src = wv + (size_t)(wr - 2560) * 2048 + k;
        dptr = wb + (size_t)(rb - 256) * 32768 + tin;
    }
    float4 a = *(const float4*)src;
    float4 b = *(const float4*)(src + 4);
    bf16x8 r;
    r[0] = (__bf16)a.x; r[1] = (__bf16)a.y; r[2] = (__bf16)a.z; r[3] = (__bf16)a.w;
    r[4] = (__bf16)b.x; r[5] = (__bf16)b.y; r[6] = (__bf16)b.z; r[7] = (__bf16)b.w;
    *(bf16x8*)dptr = r;
}

// ---------------------------------------------------------------------------
// Fused QKV GEMM v5 = round-7 v4 (passed) with TILED staging sources.
// 128x128/BK=32 one-syncthreads double-buffer, 512 thr = 8 waves (4Mx2N),
// per-wave out 32x64 = acc[2][4], grid 768 = 3 blocks/CU. A/B are now in
// frag-tile order: stage() GLL16 source = tile base + lane*16B — contiguous
// 1KB per instruction (was 16 x 64B at 4KB stride). LDS contents, MFMA loop,
// epilogue byte-identical to round-7.
// Epilogue routes by tn: tn<16 Q row-major (scaled); 16-19 K frag-order;
// 20-23 V frag-order.
// ---------------------------------------------------------------------------
__global__ __launch_bounds__(512, 6) void gemm_qkv(const __bf16* __restrict__ A,
                                                   const __bf16* __restrict__ B,
                                                   __bf16* __restrict__ Qb,
                                                   __bf16* __restrict__ Kf,
                                                   __bf16* __restrict__ Vf,
                                                   float qscale) {
    __shared__ __bf16 As[2 * 4096];   // 16 KB: [buf][subtile 0..7][512]
    __shared__ __bf16 Bs[2 * 4096];   // 16 KB

    int tid = threadIdx.x;
    int wave = tid >> 6, lane = tid & 63;
    int quad = lane >> 4, l16 = lane & 15;
    int wr = wave >> 1, wc = wave & 1;   // 4x2 wave grid

    int tm = blockIdx.x & 31, tn = blockIdx.x >> 5;   // 32 x 24

    // tiled bases: row-block (tm*8+wave) has 64 k-tiles of 512 elems
    const __bf16* Atile = A + (size_t)(tm * 8 + wave) * 32768 + lane * 8;
    const __bf16* Btile = B + (size_t)(tn * 8 + wave) * 32768 + lane * 8;

    f32x4 acc[2][4] = {};

    // each wave stages its 16x32 subtile of A and B: contiguous 1KB GLL16s
    auto stage = [&](int kb, int buf) {
        GLL16(Atile + (size_t)kb * 512, As + buf * 4096 + wave * 512 + lane * 8);
        GLL16(Btile + (size_t)kb * 512, Bs + buf * 4096 + wave * 512 + lane * 8);
    };

    const int nk = 64;
    stage(0, 0);
    for (int it = 0; it < nk; ++it) {
        __syncthreads();     // drains vmcnt -> buf it&1 fully staged; WAR-safe
        if (it + 1 < nk) stage(it + 1, (it + 1) & 1);
        const __bf16* Ab = As + (it & 1) * 4096;
        const __bf16* Bb = Bs + (it & 1) * 4096;
        bf16x8 af[2], bfr[4];
#pragma unroll
        for (int m = 0; m < 2; ++m)
            af[m] = *(const bf16x8*)(Ab + (wr * 2 + m) * 512 + lane * 8);
#pragma unroll
        for (int n = 0; n < 4; ++n)
            bfr[n] = *(const bf16x8*)(Bb + (wc * 4 + n) * 512 + lane * 8);
#pragma unroll
        for (int m = 0; m < 2; ++m)
#pragma unroll
            for (int n = 0; n < 4; ++n)
                acc[m][n] = MFMA16(af[m], bfr[n], acc[m][n]);
    }

    // ---- epilogue: route by tn (verbatim round-0/7 formulas) ----
#pragma unroll
    for (int m = 0; m < 2; ++m) {
        int row0 = tm * 128 + wr * 32 + m * 16 + quad * 4;
        int bb = row0 >> 11, tok0 = row0 & 2047;
#pragma unroll
        for (int n = 0; n < 4; ++n) {
            int col = tn * 128 + wc * 64 + n * 16 + l16;
            if (tn < 16) {                       // ---- Q, row-major ----
#pragma unroll
                for (int r = 0; r < 4; ++r)
                    Qb[(size_t)(row0 + r) * 2048 + col] = (__bf16)(acc[m][n][r] * qscale);
            } else if (tn < 20) {                // ---- K frag-order ----
                int d_all = col - 2048;
                int g = d_all >> 7, dd = d_all & 127;
                int dt = dd >> 5, q4 = (dd >> 3) & 3, jj = dd & 7;
                int tb = tok0 >> 4, tl0 = tok0 & 15;
                __bf16* base = Kf + ((((size_t)(bb * 4 + g) * 128 + tb) * 4 + dt) * 512)
                               + (q4 * 16 + tl0) * 8 + jj;
#pragma unroll
                for (int r = 0; r < 4; ++r)
                    base[r * 8] = (__bf16)acc[m][n][r];
            } else {                             // ---- V frag-order ----
                int d_all = col - 2560;
                int g = d_all >> 7, dd = d_all & 127;
                int nto = dd >> 4, dl = dd & 15;
                int ch = tok0 >> 6, kk = (tok0 >> 5) & 1;
                int q4v = (tok0 >> 3) & 3, jv0 = tok0 & 7;
                size_t off = ((((size_t)(bb * 4 + g) * 32 + ch) * 16) + nto * 2 + kk) * 512
                             + (q4v * 16 + dl) * 8 + jv0;
                short4 pk;
                pk.x = bf_s(acc[m][n][0]); pk.y = bf_s(acc[m][n][1]);
                pk.z = bf_s(acc[m][n][2]); pk.w = bf_s(acc[m][n][3]);
                *(short4*)(Vf + off) = pk;
            }
        }
    }
}

// ---------------------------------------------------------------------------
// Flash attention — UNCHANGED round-4/5/7 kernel (passed 3x). Single-lane
// discipline: only gemm staging changed this round. attn should surface in
// the rocprof top-5 once gemm drops below it.
// ---------------------------------------------------------------------------
__global__ __launch_bounds__(256) void attn_mfma(const __bf16* __restrict__ Q,
                                                 const __bf16* __restrict__ Kf,
                                                 const __bf16* __restrict__ Vf,
                                                 float* __restrict__ O) {
    const int T = 2048, CM = 2048, HD = 128;
    __shared__ __bf16 Ks[2 * 8192];   // 32 KB: buf | fb = t*4+dt
    __shared__ __bf16 Vs[2 * 8192];   // 32 KB: buf | fb = nto*2+kk
    __shared__ __bf16 Pl[8192];       // 4 KB/wave: fb = mt*2+kk

    int tid = threadIdx.x;
    int wave = tid >> 6, lane = tid & 63;
    int quad = lane >> 4, l16 = lane & 15;

    int bg = blockIdx.x & 7;
    int slot = blockIdx.x >> 3;
    int qb = (slot < 32) ? (63 - slot) : (slot - 32);
    int b = bg >> 2, g = bg & 3;
    int h = g * 4 + wave;
    int q0 = qb * 32;

    bf16x8 qf[2][4];
    const __bf16* qbase = Q + (size_t)b * T * CM + (size_t)h * HD;
#pragma unroll
    for (int nt = 0; nt < 2; ++nt)
#pragma unroll
        for (int dt = 0; dt < 4; ++dt)
            qf[nt][dt] = *(const bf16x8*)(qbase + (size_t)(q0 + nt * 16 + l16) * CM
                                          + dt * 32 + quad * 8);

    const __bf16* kcb = Kf + (size_t)(b * 4 + g) * 262144;
    const __bf16* vcb = Vf + (size_t)(b * 4 + g) * 262144;

    float m_r[2] = {-1e30f, -1e30f}, l_r[2] = {0.f, 0.f};
    f32x4 o_acc[2][8] = {};
    __bf16* Pw = Pl + wave * 2048;

    auto stage_kv = [&](int ch, int buf) {
        const __bf16* kg = kcb + ch * 8192 + wave * 2048 + lane * 8;
        const __bf16* vg = vcb + ch * 8192 + wave * 2048 + lane * 8;
        __bf16* kl = Ks + buf * 8192 + wave * 2048 + lane * 8;
        __bf16* vl = Vs + buf * 8192 + wave * 2048 + lane * 8;
#pragma unroll
        for (int i = 0; i < 4; ++i) GLL16(kg + i * 512, kl + i * 512);
#pragma unroll
        for (int i = 0; i < 4; ++i) GLL16(vg + i * 512, vl + i * 512);
    };

    int nch = (qb >> 1) + 1;
    stage_kv(0, 0);
    for (int ch = 0; ch < nch; ++ch) {
        // barrier #1: every wave finished reading buf (ch+1)&1 (= chunk ch-1)
        BAR();
        if (ch + 1 < nch) {
            stage_kv(ch + 1, (ch + 1) & 1);
            WAIT_VM(8);   // chunk ch's 8 loads older than the 8 just issued
        } else {
            WAIT_VM(0);
        }
        // barrier #2: rendezvous -> ALL waves' chunk-ch loads are in LDS
        BAR();

        const __bf16* Kb = Ks + (ch & 1) * 8192;
        const __bf16* Vb = Vs + (ch & 1) * 8192;

        // ---- S^T = K·Q^T ----
        f32x4 st[2][4] = {};
        __builtin_amdgcn_s_setprio(1);
#pragma unroll
        for (int t = 0; t < 4; ++t)
#pragma unroll
            for (int dt = 0; dt < 4; ++dt) {
                bf16x8 kfv = *(const bf16x8*)(Kb + (t * 4 + dt) * 512 + lane * 8);
                st[0][t] = MFMA16(kfv, qf[0][dt], st[0][t]);
                st[1][t] = MFMA16(kfv, qf[1][dt], st[1][t]);
            }
        __builtin_amdgcn_s_setprio(0);

        bool diag = (ch == nch - 1);
        float alpha[2];
#pragma unroll
        for (int nt = 0; nt < 2; ++nt) {
            if (diag) {
                int qg = q0 + nt * 16 + l16;
#pragma unroll
                for (int t = 0; t < 4; ++t)
#pragma unroll
                    for (int r = 0; r < 4; ++r)
                        if (ch * 64 + t * 16 + quad * 4 + r > qg) st[nt][t][r] = -1e30f;
            }
            float cmax = -1e30f;
#pragma unroll
            for (int t = 0; t < 4; ++t)
                cmax = fmaxf(cmax, fmaxf(fmaxf(st[nt][t][0], st[nt][t][1]),
                                         fmaxf(st[nt][t][2], st[nt][t][3])));
            cmax = fmaxf(cmax, __shfl_xor(cmax, 16));
            cmax = fmaxf(cmax, __shfl_xor(cmax, 32));
            float mnew = fmaxf(m_r[nt], cmax);
            alpha[nt] = __expf(m_r[nt] - mnew);
            m_r[nt] = mnew;
            float ps = 0.f;
#pragma unroll
            for (int t = 0; t < 4; ++t) {
                float p0 = __expf(st[nt][t][0] - mnew);
                float p1 = __expf(st[nt][t][1] - mnew);
                float p2 = __expf(st[nt][t][2] - mnew);
                float p3 = __expf(st[nt][t][3] - mnew);
                ps += (p0 + p1) + (p2 + p3);
                int off = (nt * 2 + (t >> 1)) * 512 + ((t & 1) * 2 + (quad >> 1)) * 128
                          + l16 * 8 + (quad & 1) * 4;
                unsigned long long pk =
                    (unsigned long long)pack_bf16(p0, p1) |
                    ((unsigned long long)pack_bf16(p2, p3) << 32);
                *(unsigned long long*)(Pw + off) = pk;
            }
            ps += __shfl_xor(ps, 16);
            ps += __shfl_xor(ps, 32);
            l_r[nt] = l_r[nt] * alpha[nt] + ps;
        }

        // ---- rescale O ----
#pragma unroll
        for (int mt = 0; mt < 2; ++mt)
#pragma unroll
            for (int r = 0; r < 4; ++r) {
                float alr = __shfl(alpha[mt], quad * 4 + r);
#pragma unroll
                for (int nto = 0; nto < 8; ++nto)
                    o_acc[mt][nto][r] *= alr;
            }

        // ---- O += P·V (P wave-private: no barrier; lgkmcnt orders WAR/RAW) ----
        __builtin_amdgcn_s_setprio(1);
#pragma unroll
        for (int mt = 0; mt < 2; ++mt)
#pragma unroll
            for (int kk = 0; kk < 2; ++kk) {
                bf16x8 pf = *(const bf16x8*)(Pw + (mt * 2 + kk) * 512 + lane * 8);
#pragma unroll
                for (int nto = 0; nto < 8; ++nto) {
                    bf16x8 vf = *(const bf16x8*)(Vb + (nto * 2 + kk) * 512 + lane * 8);
                    o_acc[mt][nto] = MFMA16(pf, vf, o_acc[mt][nto]);
                }
            }
        __builtin_amdgcn_s_setprio(0);
    }

    float* obase = O + (size_t)b * T * CM + (size_t)h * HD;
#pragma unroll
    for (int mt = 0; mt < 2; ++mt) {
        float invl = 1.f / l_r[mt];
#pragma unroll
        for (int r = 0; r < 4; ++r) {
            float ir = __shfl(invl, quad * 4 + r);
            float* orow = obase + (size_t)(q0 + 16 * mt + quad * 4 + r) * CM;
#pragma unroll
            for (int nto = 0; nto < 8; ++nto)
                orow[nto * 16 + l16] = o_acc[mt][nto][r] * ir;
        }
    }
}

extern "C" void kernel_launch(void* const* d_in, const int* in_sizes, int n_in,
                              void* d_out, int out_size, void* d_ws, size_t ws_size,
                              hipStream_t stream) {
    const float* x  = (const float*)d_in[0];
    const float* Wq = (const float*)d_in[1];
    const float* Wk = (const float*)d_in[2];
    const float* Wv = (const float*)d_in[3];
    float* out = (float*)d_out;

    const float qscale = 0.08838834764831845f;  // 128^-0.5

    __bf16* xb = (__bf16*)d_ws;              // 8M elems, frag-tiled [256 rb][64 kb][512]
    __bf16* Wb = xb + 8388608;               // 6M, frag-tiled [192 rb][64 kb][512]
    __bf16* Qb = Wb + 6291456;               // 8M  [4096][2048] row-major
    __bf16* Kfr = Qb + 8388608;              // 2M  frag-order K
    __bf16* Vfr = Kfr + 2097152;             // 2M  frag-order V

    cvt_all<<<7168, 256, 0, stream>>>(x, Wq, Wk, Wv, xb, Wb);
    gemm_qkv<<<768, 512, 0, stream>>>(xb, Wb, Qb, Kfr, Vfr, qscale);
    attn_mfma<<<512, 256, 0, stream>>>(Qb, Kfr, Vfr, out);
}